// Round 6
// baseline (462.436 us; speedup 1.0000x reference)
//
#include <hip/hip_runtime.h>
#include <math.h>

typedef __attribute__((ext_vector_type(8))) short bf16x8;
typedef __attribute__((ext_vector_type(4))) float f32x4;

__device__ __forceinline__ unsigned short f2bf(float x) {
  union { float f; unsigned int u; } v; v.f = x;
  unsigned int r = v.u + 0x7fffu + ((v.u >> 16) & 1u);
  return (unsigned short)(r >> 16);
}
__device__ __forceinline__ float bf2f(unsigned short b) {
  union { unsigned int u; float f; } v; v.u = ((unsigned int)b) << 16; return v.f;
}
__device__ __forceinline__ void split2(float x, unsigned short& h, unsigned short& l) {
  h = f2bf(x);
  l = f2bf(x - bf2f(h));
}
__device__ __forceinline__ int fsi(int q, int c) { return q * 256 + (c ^ ((q & 7) << 2)); }

// ---------------- pooling (2x2 mean) ----------------
__global__ __launch_bounds__(256) void pool2x2(const float* __restrict__ in, float* __restrict__ out,
                                               int h, int w, int total)
{
  int i = blockIdx.x * 256 + threadIdx.x;
  if (i >= total) return;
  int x = i % w; int r = i / w; int y = r % h; int ci = r / h;
  const float* p = in + (size_t)ci * (4 * h * w) + (size_t)(2 * y) * (2 * w) + 2 * x;
  out[i] = (p[0] + p[1] + p[2 * w] + p[2 * w + 1]) * 0.25f;
}

// ---------------- merged weight prep ----------------
__global__ __launch_bounds__(256) void prep(
    const float* __restrict__ wo, const float* __restrict__ bo,
    const float* __restrict__ wa, const float* __restrict__ ba,
    const float* __restrict__ wout, const float* __restrict__ wts1, const float* __restrict__ wts2,
    const float* __restrict__ wfpn, const float* __restrict__ wval,
    const float* __restrict__ cams, const float* __restrict__ lev,
    const float* __restrict__ bfpn, const float* __restrict__ bval,
    unsigned short* __restrict__ wcatH, unsigned short* __restrict__ wcatL, float* __restrict__ bcat,
    unsigned short* __restrict__ woutH, unsigned short* __restrict__ woutL,
    unsigned short* __restrict__ wts1H, unsigned short* __restrict__ wts1L,
    unsigned short* __restrict__ wts2H, unsigned short* __restrict__ wts2L,
    unsigned short* __restrict__ wcombH, unsigned short* __restrict__ wcombL,
    float* __restrict__ e2)
{
  int bb = blockIdx.x, t = threadIdx.x;
  if (bb < 768) { // wcombT[l][n][k] = (wfpn[l]@wval)^T split
    int l = bb >> 8, i = bb & 255, j = t;
    const float* a = wfpn + ((size_t)l * 256 + i) * 256;
    float acc = 0.f;
    for (int k = 0; k < 256; ++k) acc = fmaf(a[k], wval[(size_t)k * 256 + j], acc);
    unsigned short h, lo; split2(acc, h, lo);
    size_t o = ((size_t)l * 256 + j) * 256 + i;
    wcombH[o] = h; wcombL[o] = lo;
  } else if (bb < 1056) { // wcatT (288,256) split + bcat
    int i = (bb - 768) * 256 + t;
    int c = i >> 8, k = i & 255;
    float v = (c < 192) ? wo[k * 192 + c] : wa[k * 96 + (c - 192)];
    unsigned short h, l; split2(v, h, l);
    wcatH[i] = h; wcatL[i] = l;
    if (i < 288) bcat[i] = (i < 192) ? bo[i] : ba[i - 192];
  } else if (bb < 1824) { // conv_w for wout/wts1/wts2
    int sel = (bb - 1056) >> 8;
    int i = ((bb - 1056) & 255) * 256 + t;
    int nn = i >> 8, k = i & 255;
    const float* B = (sel == 0) ? wout : (sel == 1) ? wts1 : wts2;
    unsigned short* H = (sel == 0) ? woutH : (sel == 1) ? wts1H : wts2H;
    unsigned short* L = (sel == 0) ? woutL : (sel == 1) ? wts1L : wts2L;
    float v = B[(size_t)k * 256 + nn];
    unsigned short h, l; split2(v, h, l);
    H[i] = h; L[i] = l;
  } else { // e2
    int e = bb - 1824;
    int n = e / 3, l = e % 3, j = t;
    float acc = bval[j];
    for (int k = 0; k < 256; ++k) {
      float s = cams[n * 256 + k] + lev[l * 256 + k] + bfpn[l * 256 + k];
      acc = fmaf(s, wval[(size_t)k * 256 + j], acc);
    }
    e2[(size_t)e * 256 + j] = acc;
  }
}

// ---------------- fused value kernel ----------------
__global__ __launch_bounds__(512) void value_fused(
    const float* __restrict__ img0, const float* __restrict__ cur1, const float* __restrict__ cur2,
    const unsigned short* __restrict__ wcH, const unsigned short* __restrict__ wcL,
    const float* __restrict__ e2, float* __restrict__ V)
{
  __shared__ __align__(16) unsigned short AS[2][32][32][8];
  int t = threadIdx.x, wid = t >> 6, lane = t & 63, l15 = lane & 15, lk = lane >> 4;
  int bx = blockIdx.x, cam = blockIdx.y;
  int level, tb, hw; const float* src;
  if (bx < 88)       { level = 0; tb = bx;       hw = 2816; src = img0; }
  else if (bx < 110) { level = 1; tb = bx - 88;  hw = 704;  src = cur1; }
  else               { level = 2; tb = bx - 110; hw = 176;  src = cur2; }
  int p0 = tb * 32;
  const int LST[3] = {0, 2816, 3520};
  src += (size_t)cam * 256 * hw;

  { // stage: (k-major) -> LDS (pos, k) hi/lo
    int f4g = t & 7, kb = t >> 3;  // kb 0..63
    bool full = (p0 + 32 <= hw);
#pragma unroll
    for (int j = 0; j < 4; ++j) {
      int k = kb + j * 64;
      const float* row = src + (size_t)k * hw;
      int p = p0 + 4 * f4g;
      float4 v;
      if (full) v = *(const float4*)(row + p);
      else {
        v.x = (p < hw) ? row[p] : 0.f;     v.y = (p + 1 < hw) ? row[p + 1] : 0.f;
        v.z = (p + 2 < hw) ? row[p + 2] : 0.f; v.w = (p + 3 < hw) ? row[p + 3] : 0.f;
      }
      int ch = k >> 3, ko = k & 7;
      unsigned short h, l;
      split2(v.x, h, l); AS[0][ch][4 * f4g + 0][ko] = h; AS[1][ch][4 * f4g + 0][ko] = l;
      split2(v.y, h, l); AS[0][ch][4 * f4g + 1][ko] = h; AS[1][ch][4 * f4g + 1][ko] = l;
      split2(v.z, h, l); AS[0][ch][4 * f4g + 2][ko] = h; AS[1][ch][4 * f4g + 2][ko] = l;
      split2(v.w, h, l); AS[0][ch][4 * f4g + 3][ko] = h; AS[1][ch][4 * f4g + 3][ko] = l;
    }
  }

  const unsigned short* AH = wcH + (size_t)level * 65536;
  const unsigned short* AL = wcL + (size_t)level * 65536;
  // preload weights into registers (burst)
  bf16x8 wah[16], wal[16];
#pragma unroll
  for (int mf = 0; mf < 2; ++mf)
#pragma unroll
    for (int ks = 0; ks < 8; ++ks) {
      size_t bo = (size_t)(wid * 32 + mf * 16 + l15) * 256 + ks * 32 + lk * 8;
      wah[mf * 8 + ks] = *(const bf16x8*)(AH + bo);
      wal[mf * 8 + ks] = *(const bf16x8*)(AL + bo);
    }
  __syncthreads();

  f32x4 zed = {0.f, 0.f, 0.f, 0.f};
  f32x4 acc[2][2];
#pragma unroll
  for (int mf = 0; mf < 2; ++mf)
#pragma unroll
    for (int nf = 0; nf < 2; ++nf) acc[mf][nf] = zed;
#pragma unroll
  for (int ks = 0; ks < 8; ++ks) {
    bf16x8 bqh[2], bql[2];
#pragma unroll
    for (int nf = 0; nf < 2; ++nf) {
      bqh[nf] = *(const bf16x8*)&AS[0][ks * 4 + lk][nf * 16 + l15][0];
      bql[nf] = *(const bf16x8*)&AS[1][ks * 4 + lk][nf * 16 + l15][0];
    }
#pragma unroll
    for (int mf = 0; mf < 2; ++mf) {
#pragma unroll
      for (int nf = 0; nf < 2; ++nf) {
        acc[mf][nf] = __builtin_amdgcn_mfma_f32_16x16x32_bf16(wah[mf * 8 + ks], bqh[nf], acc[mf][nf], 0, 0, 0);
        acc[mf][nf] = __builtin_amdgcn_mfma_f32_16x16x32_bf16(wah[mf * 8 + ks], bql[nf], acc[mf][nf], 0, 0, 0);
        acc[mf][nf] = __builtin_amdgcn_mfma_f32_16x16x32_bf16(wal[mf * 8 + ks], bqh[nf], acc[mf][nf], 0, 0, 0);
      }
    }
  }
  // epilogue: row=out-channel, col=pos
  const float* bias = e2 + (size_t)(cam * 3 + level) * 256;
  float* Vb = V + ((size_t)cam * 3696 + LST[level] + p0) * 256;
  int lg = lane >> 4;
#pragma unroll
  for (int mf = 0; mf < 2; ++mf) {
    int chb = wid * 32 + mf * 16 + lg * 4;
    float4 b4 = *(const float4*)(bias + chb);
#pragma unroll
    for (int nf = 0; nf < 2; ++nf) {
      int q = nf * 16 + l15;
      if (p0 + q >= hw) continue;
      float4 o;
      o.x = acc[mf][nf][0] + b4.x; o.y = acc[mf][nf][1] + b4.y;
      o.z = acc[mf][nf][2] + b4.z; o.w = acc[mf][nf][3] + b4.w;
      *(float4*)(Vb + (size_t)q * 256 + chb) = o;
    }
  }
}

// ---------------- fused iteration kernel (512 threads, 8 waves) ----------------
// LDS: AS (split-bf16 activations, 32KB) + FS (f32 staging, 32KB XOR-swizzled [32][256])
__global__ __launch_bounds__(512) void fused_iter(
    const float* __restrict__ slots, const float* __restrict__ qin, const float* __restrict__ pos,
    const unsigned short* __restrict__ woutH, const unsigned short* __restrict__ woutL,
    const unsigned short* __restrict__ wts1H, const unsigned short* __restrict__ wts1L,
    const unsigned short* __restrict__ wts2H, const unsigned short* __restrict__ wts2L,
    const unsigned short* __restrict__ wcatH, const unsigned short* __restrict__ wcatL,
    const float* __restrict__ bout, const float* __restrict__ bts1,
    const float* __restrict__ bts2, const float* __restrict__ bcat,
    float* __restrict__ qout, float* __restrict__ outA, float* __restrict__ outB,
    float* __restrict__ qtmpA, float* __restrict__ qtmpB, int init)
{
  __shared__ __align__(16) unsigned short AS[2][32][32][8]; // 32 KB
  __shared__ __align__(16) float FS[8192];                  // 32 KB
  int t = threadIdx.x, wid = t >> 6, lane = t & 63, l15 = lane & 15, lk = lane >> 4;
  int lg = lk;
  int r0 = blockIdx.x * 32;
  int rl = t & 31;
  int rg = r0 + rl; int rc = rg > 9999 ? 9999 : rg;
  // coalesced-lane mapping for FS
  int cq = t >> 4, cc0 = (t & 15) * 16;
  int cqg = r0 + cq; int cqc = cqg > 9999 ? 9999 : cqg;

  bf16x8 wah[16], wal[16];
  f32x4 zed = {0.f, 0.f, 0.f, 0.f};
  f32x4 acc[2][2];

  auto preload = [&](const unsigned short* AH, const unsigned short* AL) {
#pragma unroll
    for (int mf = 0; mf < 2; ++mf)
#pragma unroll
      for (int ks = 0; ks < 8; ++ks) {
        size_t bo = (size_t)(wid * 32 + mf * 16 + l15) * 256 + ks * 32 + lk * 8;
        wah[mf * 8 + ks] = *(const bf16x8*)(AH + bo);
        wal[mf * 8 + ks] = *(const bf16x8*)(AL + bo);
      }
  };
  auto mfmaloop = [&]() {
#pragma unroll
    for (int mf = 0; mf < 2; ++mf)
#pragma unroll
      for (int nf = 0; nf < 2; ++nf) acc[mf][nf] = zed;
#pragma unroll
    for (int ks = 0; ks < 8; ++ks) {
      bf16x8 bqh[2], bql[2];
#pragma unroll
      for (int nf = 0; nf < 2; ++nf) {
        bqh[nf] = *(const bf16x8*)&AS[0][ks * 4 + lk][nf * 16 + l15][0];
        bql[nf] = *(const bf16x8*)&AS[1][ks * 4 + lk][nf * 16 + l15][0];
      }
#pragma unroll
      for (int mf = 0; mf < 2; ++mf) {
#pragma unroll
        for (int nf = 0; nf < 2; ++nf) {
          acc[mf][nf] = __builtin_amdgcn_mfma_f32_16x16x32_bf16(wah[mf * 8 + ks], bqh[nf], acc[mf][nf], 0, 0, 0);
          acc[mf][nf] = __builtin_amdgcn_mfma_f32_16x16x32_bf16(wah[mf * 8 + ks], bql[nf], acc[mf][nf], 0, 0, 0);
          acc[mf][nf] = __builtin_amdgcn_mfma_f32_16x16x32_bf16(wal[mf * 8 + ks], bqh[nf], acc[mf][nf], 0, 0, 0);
        }
      }
    }
  };

  // ---- phase 0: stage B-side (queries) into AS; residual into FS; preload first weights ----
  {
    int cb2 = (t >> 5) * 2;
    const float* base = (init ? qin : slots) + (size_t)rc * 256;
    const float* pbase = pos + (size_t)rc * 256;
#pragma unroll
    for (int j = 0; j < 2; ++j) {
      int ch = cb2 + j, k0 = ch * 8;
      float4 a0 = *(const float4*)(base + k0);
      float4 a1 = *(const float4*)(base + k0 + 4);
      if (init) {
        float4 p0v = *(const float4*)(pbase + k0);
        float4 p1v = *(const float4*)(pbase + k0 + 4);
        a0.x += p0v.x; a0.y += p0v.y; a0.z += p0v.z; a0.w += p0v.w;
        a1.x += p1v.x; a1.y += p1v.y; a1.z += p1v.z; a1.w += p1v.w;
      }
      bf16x8 hv, lv; unsigned short h, l;
      split2(a0.x, h, l); hv[0] = (short)h; lv[0] = (short)l;
      split2(a0.y, h, l); hv[1] = (short)h; lv[1] = (short)l;
      split2(a0.z, h, l); hv[2] = (short)h; lv[2] = (short)l;
      split2(a0.w, h, l); hv[3] = (short)h; lv[3] = (short)l;
      split2(a1.x, h, l); hv[4] = (short)h; lv[4] = (short)l;
      split2(a1.y, h, l); hv[5] = (short)h; lv[5] = (short)l;
      split2(a1.z, h, l); hv[6] = (short)h; lv[6] = (short)l;
      split2(a1.w, h, l); hv[7] = (short)h; lv[7] = (short)l;
      *(bf16x8*)&AS[0][ch][rl][0] = hv;
      *(bf16x8*)&AS[1][ch][rl][0] = lv;
    }
  }
  if (!init) {
    // residual qin -> FS (coalesced)
#pragma unroll
    for (int j = 0; j < 4; ++j)
      *(float4*)&FS[fsi(cq, cc0 + 4 * j)] = *(const float4*)(qin + (size_t)cqc * 256 + cc0 + 4 * j);
    preload(woutH, woutL);
  } else {
    preload(wcatH, wcatL);
  }
  __syncthreads();

  if (!init) {
    // ---- g2: slots@wout + bout + qin ----
    mfmaloop();
    preload(wts1H, wts1L);
    __syncthreads();
#pragma unroll
    for (int mf = 0; mf < 2; ++mf) {
      int chb = wid * 32 + mf * 16 + lg * 4;
      float4 b4 = *(const float4*)(bout + chb);
#pragma unroll
      for (int nf = 0; nf < 2; ++nf) {
        int q = nf * 16 + l15;
        float4 rr = *(const float4*)&FS[fsi(q, chb)];
        float v0 = acc[mf][nf][0] + b4.x + rr.x;
        float v1 = acc[mf][nf][1] + b4.y + rr.y;
        float v2 = acc[mf][nf][2] + b4.z + rr.z;
        float v3 = acc[mf][nf][3] + b4.w + rr.w;
        ushort4 hh, ll;
        split2(v0, hh.x, ll.x); split2(v1, hh.y, ll.y);
        split2(v2, hh.z, ll.z); split2(v3, hh.w, ll.w);
        *(ushort4*)&AS[0][chb >> 3][q][chb & 7] = hh;
        *(ushort4*)&AS[1][chb >> 3][q][chb & 7] = ll;
      }
    }
    __syncthreads();
    // ---- g3: relu(@wts1 + bts1) ----
    mfmaloop();
    preload(wts2H, wts2L);
    // pos -> FS (coalesced) ; FS's residual data is dead after g2 epilogue
#pragma unroll
    for (int j = 0; j < 4; ++j)
      *(float4*)&FS[fsi(cq, cc0 + 4 * j)] = *(const float4*)(pos + (size_t)cqc * 256 + cc0 + 4 * j);
    __syncthreads();
#pragma unroll
    for (int mf = 0; mf < 2; ++mf) {
      int chb = wid * 32 + mf * 16 + lg * 4;
      float4 b4 = *(const float4*)(bts1 + chb);
#pragma unroll
      for (int nf = 0; nf < 2; ++nf) {
        int q = nf * 16 + l15;
        float v0 = fmaxf(acc[mf][nf][0] + b4.x, 0.f);
        float v1 = fmaxf(acc[mf][nf][1] + b4.y, 0.f);
        float v2 = fmaxf(acc[mf][nf][2] + b4.z, 0.f);
        float v3 = fmaxf(acc[mf][nf][3] + b4.w, 0.f);
        ushort4 hh, ll;
        split2(v0, hh.x, ll.x); split2(v1, hh.y, ll.y);
        split2(v2, hh.z, ll.z); split2(v3, hh.w, ll.w);
        *(ushort4*)&AS[0][chb >> 3][q][chb & 7] = hh;
        *(ushort4*)&AS[1][chb >> 3][q][chb & 7] = ll;
      }
    }
    __syncthreads();
    // ---- g4: @wts2 + bts2 -> stage f32 into FS; stage split(o+pos) into AS ----
    mfmaloop();
    if (qtmpA) preload(wcatH, wcatL);
    __syncthreads();
#pragma unroll
    for (int mf = 0; mf < 2; ++mf) {
      int chb = wid * 32 + mf * 16 + lg * 4;
      float4 b4 = *(const float4*)(bts2 + chb);
#pragma unroll
      for (int nf = 0; nf < 2; ++nf) {
        int q = nf * 16 + l15;
        float4 pv = *(const float4*)&FS[fsi(q, chb)];  // pos (same lane owns this slot)
        float4 o;
        o.x = acc[mf][nf][0] + b4.x; o.y = acc[mf][nf][1] + b4.y;
        o.z = acc[mf][nf][2] + b4.z; o.w = acc[mf][nf][3] + b4.w;
        *(float4*)&FS[fsi(q, chb)] = o;                // qout staging (overwrite pos)
        if (qtmpA) {
          ushort4 hh, ll;
          split2(o.x + pv.x, hh.x, ll.x); split2(o.y + pv.y, hh.y, ll.y);
          split2(o.z + pv.z, hh.z, ll.z); split2(o.w + pv.w, hh.w, ll.w);
          *(ushort4*)&AS[0][chb >> 3][q][chb & 7] = hh;
          *(ushort4*)&AS[1][chb >> 3][q][chb & 7] = ll;
        }
      }
    }
    __syncthreads();
    // coalesced store of qout (+copies) from FS
    if (cqg < 10000) {
#pragma unroll
      for (int j = 0; j < 4; ++j) {
        float4 v = *(const float4*)&FS[fsi(cq, cc0 + 4 * j)];
        size_t go = (size_t)cqg * 256 + cc0 + 4 * j;
        *(float4*)(qout + go) = v;
        if (outA) { *(float4*)(outA + go) = v; *(float4*)(outB + go) = v; }
      }
    }
    if (!qtmpA) return;
  }

  // ---- g1': qp @ wcat + bcat -> qtmpA (cols 0-255) + qtmpB (cols 256-287) ----
  mfmaloop();  // main: wave wid covers cols wid*32..wid*32+31
  f32x4 acc3[2] = {zed, zed};
  if (wid < 2) {
    // extra unit: cols 256 + wid*16 .. +15 (reuse wah[0..7]/wal[0..7])
#pragma unroll
    for (int ks = 0; ks < 8; ++ks) {
      size_t bo = (size_t)(256 + wid * 16 + l15) * 256 + ks * 32 + lk * 8;
      wah[ks] = *(const bf16x8*)(wcatH + bo);
      wal[ks] = *(const bf16x8*)(wcatL + bo);
    }
#pragma unroll
    for (int ks = 0; ks < 8; ++ks) {
      bf16x8 bqh[2], bql[2];
#pragma unroll
      for (int nf = 0; nf < 2; ++nf) {
        bqh[nf] = *(const bf16x8*)&AS[0][ks * 4 + lk][nf * 16 + l15][0];
        bql[nf] = *(const bf16x8*)&AS[1][ks * 4 + lk][nf * 16 + l15][0];
      }
#pragma unroll
      for (int nf = 0; nf < 2; ++nf) {
        acc3[nf] = __builtin_amdgcn_mfma_f32_16x16x32_bf16(wah[ks], bqh[nf], acc3[nf], 0, 0, 0);
        acc3[nf] = __builtin_amdgcn_mfma_f32_16x16x32_bf16(wah[ks], bql[nf], acc3[nf], 0, 0, 0);
        acc3[nf] = __builtin_amdgcn_mfma_f32_16x16x32_bf16(wal[ks], bqh[nf], acc3[nf], 0, 0, 0);
      }
    }
  }
  __syncthreads();  // all AS reads done; safe to overwrite AS as f32 staging
  float* ASf = (float*)(&AS[0][0][0][0]);
#pragma unroll
  for (int mf = 0; mf < 2; ++mf) {
    int chb = wid * 32 + mf * 16 + lg * 4;
    float4 b4 = *(const float4*)(bcat + chb);
#pragma unroll
    for (int nf = 0; nf < 2; ++nf) {
      int q = nf * 16 + l15;
      float4 o;
      o.x = acc[mf][nf][0] + b4.x; o.y = acc[mf][nf][1] + b4.y;
      o.z = acc[mf][nf][2] + b4.z; o.w = acc[mf][nf][3] + b4.w;
      *(float4*)&ASf[fsi(q, chb)] = o;
    }
  }
  if (wid < 2) {
    int ce = 256 + wid * 16 + lg * 4;
    float4 b4 = *(const float4*)(bcat + ce);
#pragma unroll
    for (int nf = 0; nf < 2; ++nf) {
      int q = nf * 16 + l15;
      int qg = r0 + q;
      if (qg < 10000) {
        float4 o;
        o.x = acc3[nf][0] + b4.x; o.y = acc3[nf][1] + b4.y;
        o.z = acc3[nf][2] + b4.z; o.w = acc3[nf][3] + b4.w;
        *(float4*)(qtmpB + (size_t)qg * 32 + (ce - 256)) = o;
      }
    }
  }
  __syncthreads();
  if (cqg < 10000) {
#pragma unroll
    for (int j = 0; j < 4; ++j) {
      float4 v = *(const float4*)&ASf[fsi(cq, cc0 + 4 * j)];
      *(float4*)(qtmpA + (size_t)cqg * 256 + cc0 + 4 * j) = v;
    }
  }
}

// ---------------- deformable sampling + attention + cam-average -> slots ----------------
__global__ __launch_bounds__(256) void sca_sample(const float* __restrict__ qtmpA, const float* __restrict__ qtmpB,
                                                  const float* __restrict__ V,
                                                  const float* __restrict__ l2i, float* __restrict__ slots)
{
  int b = blockIdx.x;
  int q = (b & 7) * 1250 + (b >> 3);  // XCD-aware: each XCD gets contiguous BEV band
  int t = threadIdx.x;
  int head = t >> 5;
  __shared__ float raw[288];
  __shared__ float attnS[96];
  __shared__ float refx[6][4], refy[6][4];
  __shared__ int mnd[24];
  __shared__ int validn[6];
  __shared__ __align__(16) float w4[576][4];
  __shared__ __align__(16) int o4[576][4];

  raw[t] = qtmpA[(size_t)q * 256 + t];
  if (t < 32) raw[256 + t] = qtmpB[(size_t)q * 32 + t];
  if (t >= 32 && t < 56) {
    int tt = t - 32;
    int n = tt >> 2, d = tt & 3;
    const float* Mrow = l2i + n * 16;
    int qx = q % 100, qy = q / 100;
    float X = ((qx + 0.5f) / 100.0f) * 102.4f + (-51.2f);
    float Y = ((qy + 0.5f) / 100.0f) * 102.4f + (-51.2f);
    float zi = (d == 3) ? 7.5f : (0.5f + (float)d * (7.0f / 3.0f));
    float Z = zi + (-5.0f);
    float px = Mrow[0] * X + Mrow[1] * Y + Mrow[2] * Z + Mrow[3];
    float py = Mrow[4] * X + Mrow[5] * Y + Mrow[6] * Z + Mrow[7];
    float pz = Mrow[8] * X + Mrow[9] * Y + Mrow[10] * Z + Mrow[11];
    float dz = fmaxf(pz, 1e-5f);
    float xc = (px / dz) / 704.0f;
    float yc = (py / dz) / 256.0f;
    refx[n][d] = xc; refy[n][d] = yc;
    mnd[n * 4 + d] = (pz > 1e-5f) && (xc > 0.f) && (xc < 1.f) && (yc > 0.f) && (yc < 1.f);
  }
  __syncthreads();
  if (t < 8) {
    float mx = raw[192 + t * 12];
    for (int p = 1; p < 12; ++p) mx = fmaxf(mx, raw[192 + t * 12 + p]);
    float s = 0.f;
    float e[12];
#pragma unroll
    for (int p = 0; p < 12; ++p) { e[p] = __expf(raw[192 + t * 12 + p] - mx); s += e[p]; }
    float inv = 1.f / s;
#pragma unroll
    for (int p = 0; p < 12; ++p) attnS[t * 12 + p] = e[p] * inv;
  } else if (t < 14) {
    int n = t - 8;
    validn[n] = mnd[n * 4] | mnd[n * 4 + 1] | mnd[n * 4 + 2] | mnd[n * 4 + 3];
  }
  __syncthreads();

  int nv = validn[0] + validn[1] + validn[2] + validn[3] + validn[4] + validn[5];
  float invc = 1.f / (float)(nv > 1 ? nv : 1);

  const float WWf[3] = {88.f, 44.f, 22.f}, HHf[3] = {32.f, 16.f, 8.f};
  const int WWi[3] = {88, 44, 22}, STi[3] = {0, 2816, 3520};
  for (int pt = t; pt < 576; pt += 256) {
    int hd = pt & 7;
    int g = pt >> 3;
    int j = g % 12, n = g / 12;
    int l = j >> 2, d = j & 3;
    float wwf = WWf[l], hhf = HHf[l];
    int wwi = WWi[l], st = STi[l];
    float a = attnS[hd * 12 + j] * invc;
    float ox = raw[hd * 24 + l * 8 + d * 2 + 0];
    float oy = raw[hd * 24 + l * 8 + d * 2 + 1];
    float x = refx[n][d] * wwf + ox - 0.5f;
    float y = refy[n][d] * hhf + oy - 0.5f;
    float x0 = floorf(x), y0 = floorf(y);
    float fx = x - x0, fy = y - y0;
    float wx0 = 1.f - fx, wy0 = 1.f - fy;
    float vx0 = (x0 >= 0.f && x0 < wwf) ? 1.f : 0.f;
    float vx1 = (x0 + 1.f >= 0.f && x0 + 1.f < wwf) ? 1.f : 0.f;
    float vy0 = (y0 >= 0.f && y0 < hhf) ? 1.f : 0.f;
    float vy1 = (y0 + 1.f >= 0.f && y0 + 1.f < hhf) ? 1.f : 0.f;
    w4[pt][0] = a * wx0 * wy0 * vx0 * vy0;
    w4[pt][1] = a * fx * wy0 * vx1 * vy0;
    w4[pt][2] = a * wx0 * fy * vx0 * vy1;
    w4[pt][3] = a * fx * fy * vx1 * vy1;
    int ix0 = (int)fminf(fmaxf(x0, 0.f), wwf - 1.f);
    int ix1 = (int)fminf(fmaxf(x0 + 1.f, 0.f), wwf - 1.f);
    int iy0 = (int)fminf(fmaxf(y0, 0.f), hhf - 1.f);
    int iy1 = (int)fminf(fmaxf(y0 + 1.f, 0.f), hhf - 1.f);
    int rA = (st + iy0 * wwi) * 256, rB = (st + iy1 * wwi) * 256;
    o4[pt][0] = rA + ix0 * 256;
    o4[pt][1] = rA + ix1 * 256;
    o4[pt][2] = rB + ix0 * 256;
    o4[pt][3] = rB + ix1 * 256;
  }
  __syncthreads();

  float acc0 = 0.f, acc1 = 0.f;
#pragma unroll
  for (int n = 0; n < 6; ++n) {
    if (!validn[n]) continue;
    const float* Vn = V + (size_t)n * 946176 + t;
    int pb = n * 96 + head;
    float va[48];
#pragma unroll
    for (int j = 0; j < 12; ++j) {
      int4 o = *reinterpret_cast<const int4*>(&o4[pb + j * 8][0]);
      va[4 * j + 0] = Vn[o.x];
      va[4 * j + 1] = Vn[o.y];
      va[4 * j + 2] = Vn[o.z];
      va[4 * j + 3] = Vn[o.w];
    }
#pragma unroll
    for (int j = 0; j < 12; ++j) {
      float4 w = *reinterpret_cast<const float4*>(&w4[pb + j * 8][0]);
      acc0 = fmaf(w.x, va[4 * j + 0], acc0);
      acc1 = fmaf(w.y, va[4 * j + 1], acc1);
      acc0 = fmaf(w.z, va[4 * j + 2], acc0);
      acc1 = fmaf(w.w, va[4 * j + 3], acc1);
    }
  }
  slots[(size_t)q * 256 + t] = acc0 + acc1;
}

extern "C" void kernel_launch(void* const* d_in, const int* in_sizes, int n_in,
                              void* d_out, int out_size, void* d_ws, size_t ws_size,
                              hipStream_t stream)
{
  const float* imgs = (const float*)d_in[0];
  const float* l2i = (const float*)d_in[1];
  const float* bev_query = (const float*)d_in[2];
  const float* bev_pos = (const float*)d_in[3];
  const float* cams = (const float*)d_in[4];
  const float* lev = (const float*)d_in[5];
  const float* wfpn = (const float*)d_in[6];
  const float* bfpn = (const float*)d_in[7];
  const float* wval = (const float*)d_in[8];
  const float* bval = (const float*)d_in[9];
  const float* woff = (const float*)d_in[10];
  const float* boff = (const float*)d_in[11];
  const float* wattn = (const float*)d_in[12];
  const float* battn = (const float*)d_in[13];
  const float* wout = (const float*)d_in[14];
  const float* bout = (const float*)d_in[15];
  const float* wts1 = (const float*)d_in[16];
  const float* bts1 = (const float*)d_in[17];
  const float* wts2 = (const float*)d_in[18];
  const float* bts2 = (const float*)d_in[19];

  float* W = (float*)d_ws;
  size_t off = 0;
  auto alloc = [&](size_t n) { float* p = W + off; off += n; return p; };
  float* v    = alloc((size_t)6 * 3696 * 256);     // 5,677,056
  float* cur1 = alloc((size_t)12 * 256 * 16 * 44); // 2,162,688
  float* cur2 = alloc((size_t)12 * 256 * 8 * 22);  //   540,672
  float* bqA  = alloc(2560000);
  float* bqB  = alloc(2560000);
  float* qtmpA = alloc(2560000);
  float* qtmpB = alloc(320000);
  float* slots = alloc(2560000);
  float* wcatR = alloc(73728);
  float* woutR = alloc(65536);
  float* wts1R = alloc(65536);
  float* wts2R = alloc(65536);
  float* wcombR = alloc(196608);
  float* bcat = alloc(512);
  float* e2 = alloc(4608);
  (void)ws_size; (void)in_sizes; (void)n_in; (void)out_size;

  unsigned short* wcat_h = (unsigned short*)wcatR;   unsigned short* wcat_l = wcat_h + 288 * 256;
  unsigned short* wout_h = (unsigned short*)woutR;   unsigned short* wout_l = wout_h + 65536;
  unsigned short* wts1_h = (unsigned short*)wts1R;   unsigned short* wts1_l = wts1_h + 65536;
  unsigned short* wts2_h = (unsigned short*)wts2R;   unsigned short* wts2_l = wts2_h + 65536;
  unsigned short* wcomb_h = (unsigned short*)wcombR; unsigned short* wcomb_l = wcomb_h + 3 * 65536;

  float* OUT = (float*)d_out;

  // precompute
  pool2x2<<<8448, 256, 0, stream>>>(imgs, cur1, 16, 44, 2162688);
  pool2x2<<<2112, 256, 0, stream>>>(cur1, cur2, 8, 22, 540672);
  prep<<<1842, 256, 0, stream>>>(woff, boff, wattn, battn, wout, wts1, wts2, wfpn, wval,
                                 cams, lev, bfpn, bval,
                                 wcat_h, wcat_l, bcat, wout_h, wout_l, wts1_h, wts1_l,
                                 wts2_h, wts2_l, wcomb_h, wcomb_l, e2);

  // initial qtmp = (bev_query+pos)@wcat + bcat
  fused_iter<<<313, 512, 0, stream>>>(nullptr, bev_query, bev_pos,
      wout_h, wout_l, wts1_h, wts1_l, wts2_h, wts2_l, wcat_h, wcat_l,
      bout, bts1, bts2, bcat, bqA, nullptr, nullptr, qtmpA, qtmpB, 1);

  // value b0
  value_fused<<<dim3(116, 6), 512, 0, stream>>>(imgs, cur1, cur2, wcomb_h, wcomb_l, e2, v);

  // iter 1
  sca_sample<<<10000, 256, 0, stream>>>(qtmpA, qtmpB, v, l2i, slots);
  fused_iter<<<313, 512, 0, stream>>>(slots, bev_query, bev_pos,
      wout_h, wout_l, wts1_h, wts1_l, wts2_h, wts2_l, wcat_h, wcat_l,
      bout, bts1, bts2, bcat, bqA, nullptr, nullptr, qtmpA, qtmpB, 0);
  // iter 2 -> ego (bqB + d_out groups 0,1)
  sca_sample<<<10000, 256, 0, stream>>>(qtmpA, qtmpB, v, l2i, slots);
  fused_iter<<<313, 512, 0, stream>>>(slots, bqA, bev_pos,
      wout_h, wout_l, wts1_h, wts1_l, wts2_h, wts2_l, wcat_h, wcat_l,
      bout, bts1, bts2, bcat, bqB, OUT, OUT + 2560000, qtmpA, qtmpB, 0);

  // value b1
  value_fused<<<dim3(116, 6), 512, 0, stream>>>(imgs + (size_t)4325376, cur1 + (size_t)1081344,
                                                cur2 + (size_t)270336, wcomb_h, wcomb_l, e2, v);
  // iter 3 -> nb (directly into d_out)
  sca_sample<<<10000, 256, 0, stream>>>(qtmpA, qtmpB, v, l2i + 96, slots);
  fused_iter<<<313, 512, 0, stream>>>(slots, bqB, bev_pos,
      wout_h, wout_l, wts1_h, wts1_l, wts2_h, wts2_l, wcat_h, wcat_l,
      bout, bts1, bts2, bcat, OUT + 5120000, nullptr, nullptr, nullptr, nullptr, 0);
}

// Round 7
// 431.684 us; speedup vs baseline: 1.0712x; 1.0712x over previous
//
#include <hip/hip_runtime.h>
#include <math.h>

typedef __attribute__((ext_vector_type(8))) short bf16x8;
typedef __attribute__((ext_vector_type(4))) float f32x4;

__device__ __forceinline__ unsigned short f2bf(float x) {
  union { float f; unsigned int u; } v; v.f = x;
  unsigned int r = v.u + 0x7fffu + ((v.u >> 16) & 1u);
  return (unsigned short)(r >> 16);
}
__device__ __forceinline__ float bf2f(unsigned short b) {
  union { unsigned int u; float f; } v; v.u = ((unsigned int)b) << 16; return v.f;
}
__device__ __forceinline__ void split2(float x, unsigned short& h, unsigned short& l) {
  h = f2bf(x);
  l = f2bf(x - bf2f(h));
}

// ---------------- pooling (2x2 mean) ----------------
__global__ __launch_bounds__(256) void pool2x2(const float* __restrict__ in, float* __restrict__ out,
                                               int h, int w, int total)
{
  int i = blockIdx.x * 256 + threadIdx.x;
  if (i >= total) return;
  int x = i % w; int r = i / w; int y = r % h; int ci = r / h;
  const float* p = in + (size_t)ci * (4 * h * w) + (size_t)(2 * y) * (2 * w) + 2 * x;
  out[i] = (p[0] + p[1] + p[2 * w] + p[2 * w + 1]) * 0.25f;
}

// ---------------- merged weight prep ----------------
__global__ __launch_bounds__(256) void prep(
    const float* __restrict__ wo, const float* __restrict__ bo,
    const float* __restrict__ wa, const float* __restrict__ ba,
    const float* __restrict__ wout, const float* __restrict__ wts1, const float* __restrict__ wts2,
    const float* __restrict__ wfpn, const float* __restrict__ wval,
    const float* __restrict__ cams, const float* __restrict__ lev,
    const float* __restrict__ bfpn, const float* __restrict__ bval,
    unsigned short* __restrict__ wcatH, unsigned short* __restrict__ wcatL, float* __restrict__ bcat,
    unsigned short* __restrict__ woutH, unsigned short* __restrict__ woutL,
    unsigned short* __restrict__ wts1H, unsigned short* __restrict__ wts1L,
    unsigned short* __restrict__ wts2H, unsigned short* __restrict__ wts2L,
    unsigned short* __restrict__ wcombH, unsigned short* __restrict__ wcombL,
    float* __restrict__ e2)
{
  int bb = blockIdx.x, t = threadIdx.x;
  if (bb < 768) { // wcombT[l][n][k] = (wfpn[l]@wval)^T split
    int l = bb >> 8, i = bb & 255, j = t;
    const float* a = wfpn + ((size_t)l * 256 + i) * 256;
    float acc = 0.f;
    for (int k = 0; k < 256; ++k) acc = fmaf(a[k], wval[(size_t)k * 256 + j], acc);
    unsigned short h, lo; split2(acc, h, lo);
    size_t o = ((size_t)l * 256 + j) * 256 + i;
    wcombH[o] = h; wcombL[o] = lo;
  } else if (bb < 1056) { // wcatT (288,256) split + bcat
    int i = (bb - 768) * 256 + t;
    int c = i >> 8, k = i & 255;
    float v = (c < 192) ? wo[k * 192 + c] : wa[k * 96 + (c - 192)];
    unsigned short h, l; split2(v, h, l);
    wcatH[i] = h; wcatL[i] = l;
    if (i < 288) bcat[i] = (i < 192) ? bo[i] : ba[i - 192];
  } else if (bb < 1824) { // conv_w for wout/wts1/wts2
    int sel = (bb - 1056) >> 8;
    int i = ((bb - 1056) & 255) * 256 + t;
    int nn = i >> 8, k = i & 255;
    const float* B = (sel == 0) ? wout : (sel == 1) ? wts1 : wts2;
    unsigned short* H = (sel == 0) ? woutH : (sel == 1) ? wts1H : wts2H;
    unsigned short* L = (sel == 0) ? woutL : (sel == 1) ? wts1L : wts2L;
    float v = B[(size_t)k * 256 + nn];
    unsigned short h, l; split2(v, h, l);
    H[i] = h; L[i] = l;
  } else { // e2
    int e = bb - 1824;
    int n = e / 3, l = e % 3, j = t;
    float acc = bval[j];
    for (int k = 0; k < 256; ++k) {
      float s = cams[n * 256 + k] + lev[l * 256 + k] + bfpn[l * 256 + k];
      acc = fmaf(s, wval[(size_t)k * 256 + j], acc);
    }
    e2[(size_t)e * 256 + j] = acc;
  }
}

// ---------------- fused value kernel ----------------
__global__ __launch_bounds__(512, 4) void value_fused(
    const float* __restrict__ img0, const float* __restrict__ cur1, const float* __restrict__ cur2,
    const unsigned short* __restrict__ wcH, const unsigned short* __restrict__ wcL,
    const float* __restrict__ e2, float* __restrict__ V)
{
  __shared__ __align__(16) unsigned short AS[2][32][32][8];
  int t = threadIdx.x, wid = t >> 6, lane = t & 63, l15 = lane & 15, lk = lane >> 4;
  int bx = blockIdx.x, cam = blockIdx.y;
  int level, tb, hw; const float* src;
  if (bx < 88)       { level = 0; tb = bx;       hw = 2816; src = img0; }
  else if (bx < 110) { level = 1; tb = bx - 88;  hw = 704;  src = cur1; }
  else               { level = 2; tb = bx - 110; hw = 176;  src = cur2; }
  int p0 = tb * 32;
  const int LST[3] = {0, 2816, 3520};
  src += (size_t)cam * 256 * hw;

  { // stage: (k-major) -> LDS (pos, k) hi/lo
    int f4g = t & 7, kb = t >> 3;  // kb 0..63
    bool full = (p0 + 32 <= hw);
#pragma unroll
    for (int j = 0; j < 4; ++j) {
      int k = kb + j * 64;
      const float* row = src + (size_t)k * hw;
      int p = p0 + 4 * f4g;
      float4 v;
      if (full) v = *(const float4*)(row + p);
      else {
        v.x = (p < hw) ? row[p] : 0.f;     v.y = (p + 1 < hw) ? row[p + 1] : 0.f;
        v.z = (p + 2 < hw) ? row[p + 2] : 0.f; v.w = (p + 3 < hw) ? row[p + 3] : 0.f;
      }
      int ch = k >> 3, ko = k & 7;
      unsigned short h, l;
      split2(v.x, h, l); AS[0][ch][4 * f4g + 0][ko] = h; AS[1][ch][4 * f4g + 0][ko] = l;
      split2(v.y, h, l); AS[0][ch][4 * f4g + 1][ko] = h; AS[1][ch][4 * f4g + 1][ko] = l;
      split2(v.z, h, l); AS[0][ch][4 * f4g + 2][ko] = h; AS[1][ch][4 * f4g + 2][ko] = l;
      split2(v.w, h, l); AS[0][ch][4 * f4g + 3][ko] = h; AS[1][ch][4 * f4g + 3][ko] = l;
    }
  }
  __syncthreads();

  int m0 = wid * 32 + l15, m1 = wid * 32 + 16 + l15;
  const unsigned short* a0 = wcH + (size_t)level * 65536 + (size_t)m0 * 256 + lk * 8;
  const unsigned short* a1 = wcL + (size_t)level * 65536 + (size_t)m0 * 256 + lk * 8;
  const unsigned short* a2 = wcH + (size_t)level * 65536 + (size_t)m1 * 256 + lk * 8;
  const unsigned short* a3 = wcL + (size_t)level * 65536 + (size_t)m1 * 256 + lk * 8;

  f32x4 zed = {0.f, 0.f, 0.f, 0.f};
  f32x4 acc[2][2];
#pragma unroll
  for (int mf = 0; mf < 2; ++mf)
#pragma unroll
    for (int nf = 0; nf < 2; ++nf) acc[mf][nf] = zed;

  bf16x8 h0[8], l0[8], h1[8], l1[8];
#pragma unroll
  for (int p = 0; p < 2; ++p) {
    h0[p] = *(const bf16x8*)(a0 + p * 32);
    l0[p] = *(const bf16x8*)(a1 + p * 32);
    h1[p] = *(const bf16x8*)(a2 + p * 32);
    l1[p] = *(const bf16x8*)(a3 + p * 32);
  }
#pragma unroll
  for (int ks = 0; ks < 8; ++ks) {
    if (ks < 6) {
      h0[ks + 2] = *(const bf16x8*)(a0 + (ks + 2) * 32);
      l0[ks + 2] = *(const bf16x8*)(a1 + (ks + 2) * 32);
      h1[ks + 2] = *(const bf16x8*)(a2 + (ks + 2) * 32);
      l1[ks + 2] = *(const bf16x8*)(a3 + (ks + 2) * 32);
    }
    bf16x8 bqh[2], bql[2];
#pragma unroll
    for (int nf = 0; nf < 2; ++nf) {
      bqh[nf] = *(const bf16x8*)&AS[0][ks * 4 + lk][nf * 16 + l15][0];
      bql[nf] = *(const bf16x8*)&AS[1][ks * 4 + lk][nf * 16 + l15][0];
    }
#pragma unroll
    for (int nf = 0; nf < 2; ++nf) {
      acc[0][nf] = __builtin_amdgcn_mfma_f32_16x16x32_bf16(h0[ks], bqh[nf], acc[0][nf], 0, 0, 0);
      acc[0][nf] = __builtin_amdgcn_mfma_f32_16x16x32_bf16(h0[ks], bql[nf], acc[0][nf], 0, 0, 0);
      acc[0][nf] = __builtin_amdgcn_mfma_f32_16x16x32_bf16(l0[ks], bqh[nf], acc[0][nf], 0, 0, 0);
      acc[1][nf] = __builtin_amdgcn_mfma_f32_16x16x32_bf16(h1[ks], bqh[nf], acc[1][nf], 0, 0, 0);
      acc[1][nf] = __builtin_amdgcn_mfma_f32_16x16x32_bf16(h1[ks], bql[nf], acc[1][nf], 0, 0, 0);
      acc[1][nf] = __builtin_amdgcn_mfma_f32_16x16x32_bf16(l1[ks], bqh[nf], acc[1][nf], 0, 0, 0);
    }
  }
  // epilogue: row=out-channel, col=pos
  const float* bias = e2 + (size_t)(cam * 3 + level) * 256;
  float* Vb = V + ((size_t)cam * 3696 + LST[level] + p0) * 256;
  int lg = lane >> 4;
#pragma unroll
  for (int mf = 0; mf < 2; ++mf) {
    int chb = wid * 32 + mf * 16 + lg * 4;
    float4 b4 = *(const float4*)(bias + chb);
#pragma unroll
    for (int nf = 0; nf < 2; ++nf) {
      int q = nf * 16 + l15;
      if (p0 + q >= hw) continue;
      float4 o;
      o.x = acc[mf][nf][0] + b4.x; o.y = acc[mf][nf][1] + b4.y;
      o.z = acc[mf][nf][2] + b4.z; o.w = acc[mf][nf][3] + b4.w;
      *(float4*)(Vb + (size_t)q * 256 + chb) = o;
    }
  }
}

// ---------------- fused iteration kernel (512 threads, 8 waves) ----------------
__global__ __launch_bounds__(512, 4) void fused_iter(
    const float* __restrict__ slots, const float* __restrict__ qin, const float* __restrict__ pos,
    const unsigned short* __restrict__ woutH, const unsigned short* __restrict__ woutL,
    const unsigned short* __restrict__ wts1H, const unsigned short* __restrict__ wts1L,
    const unsigned short* __restrict__ wts2H, const unsigned short* __restrict__ wts2L,
    const unsigned short* __restrict__ wcatH, const unsigned short* __restrict__ wcatL,
    const float* __restrict__ bout, const float* __restrict__ bts1,
    const float* __restrict__ bts2, const float* __restrict__ bcat,
    float* __restrict__ qout, float* __restrict__ outA, float* __restrict__ outB,
    float* __restrict__ qtmpA, float* __restrict__ qtmpB, int init)
{
  __shared__ __align__(16) unsigned short AS[2][32][32][8]; // 32 KB
  int t = threadIdx.x, wid = t >> 6, lane = t & 63, l15 = lane & 15, lk = lane >> 4;
  int lg = lk;
  int r0 = blockIdx.x * 32;
  int rl = t & 31;
  int rg = r0 + rl; int rc = rg > 9999 ? 9999 : rg;
  int m0 = wid * 32 + l15, m1 = wid * 32 + 16 + l15;

  f32x4 zed = {0.f, 0.f, 0.f, 0.f};
  f32x4 acc[2][2];

  // 2-deep ks-pipelined GEMM phase: weights streamed from L2, B from AS.
  auto gemmP = [&](const unsigned short* __restrict__ WH, const unsigned short* __restrict__ WL) {
#pragma unroll
    for (int mf = 0; mf < 2; ++mf)
#pragma unroll
      for (int nf = 0; nf < 2; ++nf) acc[mf][nf] = zed;
    const unsigned short* a0 = WH + (size_t)m0 * 256 + lk * 8;
    const unsigned short* a1 = WL + (size_t)m0 * 256 + lk * 8;
    const unsigned short* a2 = WH + (size_t)m1 * 256 + lk * 8;
    const unsigned short* a3 = WL + (size_t)m1 * 256 + lk * 8;
    bf16x8 h0[8], l0[8], h1[8], l1[8];
#pragma unroll
    for (int p = 0; p < 2; ++p) {
      h0[p] = *(const bf16x8*)(a0 + p * 32);
      l0[p] = *(const bf16x8*)(a1 + p * 32);
      h1[p] = *(const bf16x8*)(a2 + p * 32);
      l1[p] = *(const bf16x8*)(a3 + p * 32);
    }
#pragma unroll
    for (int ks = 0; ks < 8; ++ks) {
      if (ks < 6) {
        h0[ks + 2] = *(const bf16x8*)(a0 + (ks + 2) * 32);
        l0[ks + 2] = *(const bf16x8*)(a1 + (ks + 2) * 32);
        h1[ks + 2] = *(const bf16x8*)(a2 + (ks + 2) * 32);
        l1[ks + 2] = *(const bf16x8*)(a3 + (ks + 2) * 32);
      }
      bf16x8 bqh[2], bql[2];
#pragma unroll
      for (int nf = 0; nf < 2; ++nf) {
        bqh[nf] = *(const bf16x8*)&AS[0][ks * 4 + lk][nf * 16 + l15][0];
        bql[nf] = *(const bf16x8*)&AS[1][ks * 4 + lk][nf * 16 + l15][0];
      }
#pragma unroll
      for (int nf = 0; nf < 2; ++nf) {
        acc[0][nf] = __builtin_amdgcn_mfma_f32_16x16x32_bf16(h0[ks], bqh[nf], acc[0][nf], 0, 0, 0);
        acc[0][nf] = __builtin_amdgcn_mfma_f32_16x16x32_bf16(h0[ks], bql[nf], acc[0][nf], 0, 0, 0);
        acc[0][nf] = __builtin_amdgcn_mfma_f32_16x16x32_bf16(l0[ks], bqh[nf], acc[0][nf], 0, 0, 0);
        acc[1][nf] = __builtin_amdgcn_mfma_f32_16x16x32_bf16(h1[ks], bqh[nf], acc[1][nf], 0, 0, 0);
        acc[1][nf] = __builtin_amdgcn_mfma_f32_16x16x32_bf16(h1[ks], bql[nf], acc[1][nf], 0, 0, 0);
        acc[1][nf] = __builtin_amdgcn_mfma_f32_16x16x32_bf16(l1[ks], bqh[nf], acc[1][nf], 0, 0, 0);
      }
    }
  };

  // ---- phase 0: stage B-side (queries) into AS ----
  {
    int cb2 = (t >> 5) * 2;
    const float* base = (init ? qin : slots) + (size_t)rc * 256;
    const float* pbase = pos + (size_t)rc * 256;
#pragma unroll
    for (int j = 0; j < 2; ++j) {
      int ch = cb2 + j, k0 = ch * 8;
      float4 a0 = *(const float4*)(base + k0);
      float4 a1 = *(const float4*)(base + k0 + 4);
      if (init) {
        float4 p0v = *(const float4*)(pbase + k0);
        float4 p1v = *(const float4*)(pbase + k0 + 4);
        a0.x += p0v.x; a0.y += p0v.y; a0.z += p0v.z; a0.w += p0v.w;
        a1.x += p1v.x; a1.y += p1v.y; a1.z += p1v.z; a1.w += p1v.w;
      }
      bf16x8 hv, lv; unsigned short h, l;
      split2(a0.x, h, l); hv[0] = (short)h; lv[0] = (short)l;
      split2(a0.y, h, l); hv[1] = (short)h; lv[1] = (short)l;
      split2(a0.z, h, l); hv[2] = (short)h; lv[2] = (short)l;
      split2(a0.w, h, l); hv[3] = (short)h; lv[3] = (short)l;
      split2(a1.x, h, l); hv[4] = (short)h; lv[4] = (short)l;
      split2(a1.y, h, l); hv[5] = (short)h; lv[5] = (short)l;
      split2(a1.z, h, l); hv[6] = (short)h; lv[6] = (short)l;
      split2(a1.w, h, l); hv[7] = (short)h; lv[7] = (short)l;
      *(bf16x8*)&AS[0][ch][rl][0] = hv;
      *(bf16x8*)&AS[1][ch][rl][0] = lv;
    }
  }
  __syncthreads();

  if (!init) {
    // ---- g2: slots@wout + bout + qin ----
    gemmP(woutH, woutL);
    __syncthreads();
#pragma unroll
    for (int mf = 0; mf < 2; ++mf) {
      int chb = wid * 32 + mf * 16 + lg * 4;
      float4 b4 = *(const float4*)(bout + chb);
#pragma unroll
      for (int nf = 0; nf < 2; ++nf) {
        int q = nf * 16 + l15;
        int qg = r0 + q; int qc = qg > 9999 ? 9999 : qg;
        float4 rr = *(const float4*)(qin + (size_t)qc * 256 + chb);
        float v0 = acc[mf][nf][0] + b4.x + rr.x;
        float v1 = acc[mf][nf][1] + b4.y + rr.y;
        float v2 = acc[mf][nf][2] + b4.z + rr.z;
        float v3 = acc[mf][nf][3] + b4.w + rr.w;
        ushort4 hh, ll;
        split2(v0, hh.x, ll.x); split2(v1, hh.y, ll.y);
        split2(v2, hh.z, ll.z); split2(v3, hh.w, ll.w);
        *(ushort4*)&AS[0][chb >> 3][q][chb & 7] = hh;
        *(ushort4*)&AS[1][chb >> 3][q][chb & 7] = ll;
      }
    }
    __syncthreads();
    // ---- g3: relu(@wts1 + bts1) ----
    gemmP(wts1H, wts1L);
    __syncthreads();
#pragma unroll
    for (int mf = 0; mf < 2; ++mf) {
      int chb = wid * 32 + mf * 16 + lg * 4;
      float4 b4 = *(const float4*)(bts1 + chb);
#pragma unroll
      for (int nf = 0; nf < 2; ++nf) {
        int q = nf * 16 + l15;
        float v0 = fmaxf(acc[mf][nf][0] + b4.x, 0.f);
        float v1 = fmaxf(acc[mf][nf][1] + b4.y, 0.f);
        float v2 = fmaxf(acc[mf][nf][2] + b4.z, 0.f);
        float v3 = fmaxf(acc[mf][nf][3] + b4.w, 0.f);
        ushort4 hh, ll;
        split2(v0, hh.x, ll.x); split2(v1, hh.y, ll.y);
        split2(v2, hh.z, ll.z); split2(v3, hh.w, ll.w);
        *(ushort4*)&AS[0][chb >> 3][q][chb & 7] = hh;
        *(ushort4*)&AS[1][chb >> 3][q][chb & 7] = ll;
      }
    }
    __syncthreads();
    // ---- g4: @wts2 + bts2 -> qout (+copies); stage split(o+pos) into AS ----
    gemmP(wts2H, wts2L);
    __syncthreads();
#pragma unroll
    for (int mf = 0; mf < 2; ++mf) {
      int chb = wid * 32 + mf * 16 + lg * 4;
      float4 b4 = *(const float4*)(bts2 + chb);
#pragma unroll
      for (int nf = 0; nf < 2; ++nf) {
        int q = nf * 16 + l15;
        int qg = r0 + q;
        float4 o;
        o.x = acc[mf][nf][0] + b4.x; o.y = acc[mf][nf][1] + b4.y;
        o.z = acc[mf][nf][2] + b4.z; o.w = acc[mf][nf][3] + b4.w;
        if (qg < 10000) {
          size_t go = (size_t)qg * 256 + chb;
          *(float4*)(qout + go) = o;
          if (outA) { *(float4*)(outA + go) = o; *(float4*)(outB + go) = o; }
        }
        if (qtmpA) {
          int qc = qg > 9999 ? 9999 : qg;
          float4 pv = *(const float4*)(pos + (size_t)qc * 256 + chb);
          ushort4 hh, ll;
          split2(o.x + pv.x, hh.x, ll.x); split2(o.y + pv.y, hh.y, ll.y);
          split2(o.z + pv.z, hh.z, ll.z); split2(o.w + pv.w, hh.w, ll.w);
          *(ushort4*)&AS[0][chb >> 3][q][chb & 7] = hh;
          *(ushort4*)&AS[1][chb >> 3][q][chb & 7] = ll;
        }
      }
    }
    if (!qtmpA) return;
    __syncthreads();
  }

  // ---- g1': qp @ wcat + bcat -> qtmpA (cols 0-255) + qtmpB (cols 256-287) ----
  gemmP(wcatH, wcatL);
  f32x4 acc3[2] = {zed, zed};
  if (wid < 2) {
    const unsigned short* c0 = wcatH + (size_t)(256 + wid * 16 + l15) * 256 + lk * 8;
    const unsigned short* c1 = wcatL + (size_t)(256 + wid * 16 + l15) * 256 + lk * 8;
    bf16x8 eh[8], el[8];
#pragma unroll
    for (int p = 0; p < 2; ++p) {
      eh[p] = *(const bf16x8*)(c0 + p * 32);
      el[p] = *(const bf16x8*)(c1 + p * 32);
    }
#pragma unroll
    for (int ks = 0; ks < 8; ++ks) {
      if (ks < 6) {
        eh[ks + 2] = *(const bf16x8*)(c0 + (ks + 2) * 32);
        el[ks + 2] = *(const bf16x8*)(c1 + (ks + 2) * 32);
      }
      bf16x8 bqh[2], bql[2];
#pragma unroll
      for (int nf = 0; nf < 2; ++nf) {
        bqh[nf] = *(const bf16x8*)&AS[0][ks * 4 + lk][nf * 16 + l15][0];
        bql[nf] = *(const bf16x8*)&AS[1][ks * 4 + lk][nf * 16 + l15][0];
      }
#pragma unroll
      for (int nf = 0; nf < 2; ++nf) {
        acc3[nf] = __builtin_amdgcn_mfma_f32_16x16x32_bf16(eh[ks], bqh[nf], acc3[nf], 0, 0, 0);
        acc3[nf] = __builtin_amdgcn_mfma_f32_16x16x32_bf16(eh[ks], bql[nf], acc3[nf], 0, 0, 0);
        acc3[nf] = __builtin_amdgcn_mfma_f32_16x16x32_bf16(el[ks], bqh[nf], acc3[nf], 0, 0, 0);
      }
    }
  }
#pragma unroll
  for (int mf = 0; mf < 2; ++mf) {
    int chb = wid * 32 + mf * 16 + lg * 4;
    float4 b4 = *(const float4*)(bcat + chb);
#pragma unroll
    for (int nf = 0; nf < 2; ++nf) {
      int q = nf * 16 + l15;
      int qg = r0 + q;
      if (qg >= 10000) continue;
      float4 o;
      o.x = acc[mf][nf][0] + b4.x; o.y = acc[mf][nf][1] + b4.y;
      o.z = acc[mf][nf][2] + b4.z; o.w = acc[mf][nf][3] + b4.w;
      *(float4*)(qtmpA + (size_t)qg * 256 + chb) = o;
    }
  }
  if (wid < 2) {
    int ce = 256 + wid * 16 + lg * 4;
    float4 b4 = *(const float4*)(bcat + ce);
#pragma unroll
    for (int nf = 0; nf < 2; ++nf) {
      int q = nf * 16 + l15;
      int qg = r0 + q;
      if (qg < 10000) {
        float4 o;
        o.x = acc3[nf][0] + b4.x; o.y = acc3[nf][1] + b4.y;
        o.z = acc3[nf][2] + b4.z; o.w = acc3[nf][3] + b4.w;
        *(float4*)(qtmpB + (size_t)qg * 32 + (ce - 256)) = o;
      }
    }
  }
}

// ---------------- deformable sampling + attention + cam-average -> slots ----------------
__global__ __launch_bounds__(256) void sca_sample(const float* __restrict__ qtmpA, const float* __restrict__ qtmpB,
                                                  const float* __restrict__ V,
                                                  const float* __restrict__ l2i, float* __restrict__ slots)
{
  int b = blockIdx.x;
  int q = (b & 7) * 1250 + (b >> 3);  // XCD-aware: each XCD gets contiguous BEV band
  int t = threadIdx.x;
  int head = t >> 5;
  __shared__ float raw[288];
  __shared__ float attnS[96];
  __shared__ float refx[6][4], refy[6][4];
  __shared__ int mnd[24];
  __shared__ int validn[6];
  __shared__ __align__(16) float w4[576][4];
  __shared__ __align__(16) int o4[576][4];

  raw[t] = qtmpA[(size_t)q * 256 + t];
  if (t < 32) raw[256 + t] = qtmpB[(size_t)q * 32 + t];
  if (t >= 32 && t < 56) {
    int tt = t - 32;
    int n = tt >> 2, d = tt & 3;
    const float* Mrow = l2i + n * 16;
    int qx = q % 100, qy = q / 100;
    float X = ((qx + 0.5f) / 100.0f) * 102.4f + (-51.2f);
    float Y = ((qy + 0.5f) / 100.0f) * 102.4f + (-51.2f);
    float zi = (d == 3) ? 7.5f : (0.5f + (float)d * (7.0f / 3.0f));
    float Z = zi + (-5.0f);
    float px = Mrow[0] * X + Mrow[1] * Y + Mrow[2] * Z + Mrow[3];
    float py = Mrow[4] * X + Mrow[5] * Y + Mrow[6] * Z + Mrow[7];
    float pz = Mrow[8] * X + Mrow[9] * Y + Mrow[10] * Z + Mrow[11];
    float dz = fmaxf(pz, 1e-5f);
    float xc = (px / dz) / 704.0f;
    float yc = (py / dz) / 256.0f;
    refx[n][d] = xc; refy[n][d] = yc;
    mnd[n * 4 + d] = (pz > 1e-5f) && (xc > 0.f) && (xc < 1.f) && (yc > 0.f) && (yc < 1.f);
  }
  __syncthreads();
  if (t < 8) {
    float mx = raw[192 + t * 12];
    for (int p = 1; p < 12; ++p) mx = fmaxf(mx, raw[192 + t * 12 + p]);
    float s = 0.f;
    float e[12];
#pragma unroll
    for (int p = 0; p < 12; ++p) { e[p] = __expf(raw[192 + t * 12 + p] - mx); s += e[p]; }
    float inv = 1.f / s;
#pragma unroll
    for (int p = 0; p < 12; ++p) attnS[t * 12 + p] = e[p] * inv;
  } else if (t < 14) {
    int n = t - 8;
    validn[n] = mnd[n * 4] | mnd[n * 4 + 1] | mnd[n * 4 + 2] | mnd[n * 4 + 3];
  }
  __syncthreads();

  int nv = validn[0] + validn[1] + validn[2] + validn[3] + validn[4] + validn[5];
  float invc = 1.f / (float)(nv > 1 ? nv : 1);

  const float WWf[3] = {88.f, 44.f, 22.f}, HHf[3] = {32.f, 16.f, 8.f};
  const int WWi[3] = {88, 44, 22}, STi[3] = {0, 2816, 3520};
  for (int pt = t; pt < 576; pt += 256) {
    int hd = pt & 7;
    int g = pt >> 3;
    int j = g % 12, n = g / 12;
    int l = j >> 2, d = j & 3;
    float wwf = WWf[l], hhf = HHf[l];
    int wwi = WWi[l], st = STi[l];
    float a = attnS[hd * 12 + j] * invc;
    float ox = raw[hd * 24 + l * 8 + d * 2 + 0];
    float oy = raw[hd * 24 + l * 8 + d * 2 + 1];
    float x = refx[n][d] * wwf + ox - 0.5f;
    float y = refy[n][d] * hhf + oy - 0.5f;
    float x0 = floorf(x), y0 = floorf(y);
    float fx = x - x0, fy = y - y0;
    float wx0 = 1.f - fx, wy0 = 1.f - fy;
    float vx0 = (x0 >= 0.f && x0 < wwf) ? 1.f : 0.f;
    float vx1 = (x0 + 1.f >= 0.f && x0 + 1.f < wwf) ? 1.f : 0.f;
    float vy0 = (y0 >= 0.f && y0 < hhf) ? 1.f : 0.f;
    float vy1 = (y0 + 1.f >= 0.f && y0 + 1.f < hhf) ? 1.f : 0.f;
    w4[pt][0] = a * wx0 * wy0 * vx0 * vy0;
    w4[pt][1] = a * fx * wy0 * vx1 * vy0;
    w4[pt][2] = a * wx0 * fy * vx0 * vy1;
    w4[pt][3] = a * fx * fy * vx1 * vy1;
    int ix0 = (int)fminf(fmaxf(x0, 0.f), wwf - 1.f);
    int ix1 = (int)fminf(fmaxf(x0 + 1.f, 0.f), wwf - 1.f);
    int iy0 = (int)fminf(fmaxf(y0, 0.f), hhf - 1.f);
    int iy1 = (int)fminf(fmaxf(y0 + 1.f, 0.f), hhf - 1.f);
    int rA = (st + iy0 * wwi) * 256, rB = (st + iy1 * wwi) * 256;
    o4[pt][0] = rA + ix0 * 256;
    o4[pt][1] = rA + ix1 * 256;
    o4[pt][2] = rB + ix0 * 256;
    o4[pt][3] = rB + ix1 * 256;
  }
  __syncthreads();

  float acc0 = 0.f, acc1 = 0.f;
#pragma unroll
  for (int n = 0; n < 6; ++n) {
    if (!validn[n]) continue;
    const float* Vn = V + (size_t)n * 946176 + t;
    int pb = n * 96 + head;
    float va[48];
#pragma unroll
    for (int j = 0; j < 12; ++j) {
      int4 o = *reinterpret_cast<const int4*>(&o4[pb + j * 8][0]);
      va[4 * j + 0] = Vn[o.x];
      va[4 * j + 1] = Vn[o.y];
      va[4 * j + 2] = Vn[o.z];
      va[4 * j + 3] = Vn[o.w];
    }
#pragma unroll
    for (int j = 0; j < 12; ++j) {
      float4 w = *reinterpret_cast<const float4*>(&w4[pb + j * 8][0]);
      acc0 = fmaf(w.x, va[4 * j + 0], acc0);
      acc1 = fmaf(w.y, va[4 * j + 1], acc1);
      acc0 = fmaf(w.z, va[4 * j + 2], acc0);
      acc1 = fmaf(w.w, va[4 * j + 3], acc1);
    }
  }
  slots[(size_t)q * 256 + t] = acc0 + acc1;
}

extern "C" void kernel_launch(void* const* d_in, const int* in_sizes, int n_in,
                              void* d_out, int out_size, void* d_ws, size_t ws_size,
                              hipStream_t stream)
{
  const float* imgs = (const float*)d_in[0];
  const float* l2i = (const float*)d_in[1];
  const float* bev_query = (const float*)d_in[2];
  const float* bev_pos = (const float*)d_in[3];
  const float* cams = (const float*)d_in[4];
  const float* lev = (const float*)d_in[5];
  const float* wfpn = (const float*)d_in[6];
  const float* bfpn = (const float*)d_in[7];
  const float* wval = (const float*)d_in[8];
  const float* bval = (const float*)d_in[9];
  const float* woff = (const float*)d_in[10];
  const float* boff = (const float*)d_in[11];
  const float* wattn = (const float*)d_in[12];
  const float* battn = (const float*)d_in[13];
  const float* wout = (const float*)d_in[14];
  const float* bout = (const float*)d_in[15];
  const float* wts1 = (const float*)d_in[16];
  const float* bts1 = (const float*)d_in[17];
  const float* wts2 = (const float*)d_in[18];
  const float* bts2 = (const float*)d_in[19];

  float* W = (float*)d_ws;
  size_t off = 0;
  auto alloc = [&](size_t n) { float* p = W + off; off += n; return p; };
  float* v    = alloc((size_t)6 * 3696 * 256);     // 5,677,056
  float* cur1 = alloc((size_t)12 * 256 * 16 * 44); // 2,162,688
  float* cur2 = alloc((size_t)12 * 256 * 8 * 22);  //   540,672
  float* bqA  = alloc(2560000);
  float* bqB  = alloc(2560000);
  float* qtmpA = alloc(2560000);
  float* qtmpB = alloc(320000);
  float* slots = alloc(2560000);
  float* wcatR = alloc(73728);
  float* woutR = alloc(65536);
  float* wts1R = alloc(65536);
  float* wts2R = alloc(65536);
  float* wcombR = alloc(196608);
  float* bcat = alloc(512);
  float* e2 = alloc(4608);
  (void)ws_size; (void)in_sizes; (void)n_in; (void)out_size;

  unsigned short* wcat_h = (unsigned short*)wcatR;   unsigned short* wcat_l = wcat_h + 288 * 256;
  unsigned short* wout_h = (unsigned short*)woutR;   unsigned short* wout_l = wout_h + 65536;
  unsigned short* wts1_h = (unsigned short*)wts1R;   unsigned short* wts1_l = wts1_h + 65536;
  unsigned short* wts2_h = (unsigned short*)wts2R;   unsigned short* wts2_l = wts2_h + 65536;
  unsigned short* wcomb_h = (unsigned short*)wcombR; unsigned short* wcomb_l = wcomb_h + 3 * 65536;

  float* OUT = (float*)d_out;

  // precompute
  pool2x2<<<8448, 256, 0, stream>>>(imgs, cur1, 16, 44, 2162688);
  pool2x2<<<2112, 256, 0, stream>>>(cur1, cur2, 8, 22, 540672);
  prep<<<1842, 256, 0, stream>>>(woff, boff, wattn, battn, wout, wts1, wts2, wfpn, wval,
                                 cams, lev, bfpn, bval,
                                 wcat_h, wcat_l, bcat, wout_h, wout_l, wts1_h, wts1_l,
                                 wts2_h, wts2_l, wcomb_h, wcomb_l, e2);

  // initial qtmp = (bev_query+pos)@wcat + bcat
  fused_iter<<<313, 512, 0, stream>>>(nullptr, bev_query, bev_pos,
      wout_h, wout_l, wts1_h, wts1_l, wts2_h, wts2_l, wcat_h, wcat_l,
      bout, bts1, bts2, bcat, bqA, nullptr, nullptr, qtmpA, qtmpB, 1);

  // value b0
  value_fused<<<dim3(116, 6), 512, 0, stream>>>(imgs, cur1, cur2, wcomb_h, wcomb_l, e2, v);

  // iter 1
  sca_sample<<<10000, 256, 0, stream>>>(qtmpA, qtmpB, v, l2i, slots);
  fused_iter<<<313, 512, 0, stream>>>(slots, bev_query, bev_pos,
      wout_h, wout_l, wts1_h, wts1_l, wts2_h, wts2_l, wcat_h, wcat_l,
      bout, bts1, bts2, bcat, bqA, nullptr, nullptr, qtmpA, qtmpB, 0);
  // iter 2 -> ego (bqB + d_out groups 0,1)
  sca_sample<<<10000, 256, 0, stream>>>(qtmpA, qtmpB, v, l2i, slots);
  fused_iter<<<313, 512, 0, stream>>>(slots, bqA, bev_pos,
      wout_h, wout_l, wts1_h, wts1_l, wts2_h, wts2_l, wcat_h, wcat_l,
      bout, bts1, bts2, bcat, bqB, OUT, OUT + 2560000, qtmpA, qtmpB, 0);

  // value b1
  value_fused<<<dim3(116, 6), 512, 0, stream>>>(imgs + (size_t)4325376, cur1 + (size_t)1081344,
                                                cur2 + (size_t)270336, wcomb_h, wcomb_l, e2, v);
  // iter 3 -> nb (directly into d_out)
  sca_sample<<<10000, 256, 0, stream>>>(qtmpA, qtmpB, v, l2i + 96, slots);
  fused_iter<<<313, 512, 0, stream>>>(slots, bqB, bev_pos,
      wout_h, wout_l, wts1_h, wts1_l, wts2_h, wts2_l, wcat_h, wcat_l,
      bout, bts1, bts2, bcat, OUT + 5120000, nullptr, nullptr, nullptr, nullptr, 0);
}